// Round 1
// baseline (71.805 us; speedup 1.0000x reference)
//
#include <hip/hip_runtime.h>

typedef __attribute__((ext_vector_type(8))) short bf16x8;
typedef __attribute__((ext_vector_type(4))) float f32x4;
typedef __attribute__((ext_vector_type(8))) unsigned short u16x8;

#define BB 32
#define NN 1024
#define MM 256
#define HH 128

__device__ __forceinline__ unsigned short f2bf(float f) {
  union { float f; unsigned int u; } c; c.f = f;
  unsigned int u = c.u + 0x7fffu + ((c.u >> 16) & 1u);  // RNE
  return (unsigned short)(u >> 16);
}
__device__ __forceinline__ unsigned int pack2(float lo, float hi) {
  return (unsigned int)f2bf(lo) | ((unsigned int)f2bf(hi) << 16);
}

// ---------------- h transpose: h[B][N][M] f32 -> hT[B][M][N] bf16 ----------------
__global__ __launch_bounds__(256)
void k_transpose_h(const float* __restrict__ hg, unsigned short* __restrict__ hTg) {
  __shared__ unsigned short tile[64][65];
  int bid = blockIdx.x;
  int b = bid >> 6;
  int t = bid & 63;
  int k0 = (t >> 2) << 6;   // 16 k-tiles of 64
  int m0 = (t & 3) << 6;    // 4 m-tiles of 64
  int tt = threadIdx.x;
  {
    int r = tt >> 2;
    int cg = (tt & 3) << 4;
    const float* src = hg + (((size_t)b * NN + k0 + r) * MM + m0 + cg);
#pragma unroll
    for (int i = 0; i < 4; ++i) {
      float4 v = reinterpret_cast<const float4*>(src)[i];
      tile[r][cg + i * 4 + 0] = f2bf(v.x);
      tile[r][cg + i * 4 + 1] = f2bf(v.y);
      tile[r][cg + i * 4 + 2] = f2bf(v.z);
      tile[r][cg + i * 4 + 3] = f2bf(v.w);
    }
  }
  __syncthreads();
  {
    int mr = tt >> 2;
    int kc = (tt & 3) << 4;
    alignas(16) unsigned short tmp[16];
#pragma unroll
    for (int i = 0; i < 16; ++i) tmp[i] = tile[kc + i][mr];
    unsigned short* dst = hTg + (((size_t)b * MM + m0 + mr) * NN + k0 + kc);
    *reinterpret_cast<u16x8*>(dst)     = *reinterpret_cast<u16x8*>(tmp);
    *reinterpret_cast<u16x8*>(dst + 8) = *reinterpret_cast<u16x8*>(tmp + 8);
  }
}

// ------------- W transposes: W1[M][H]->W1T[H][M], W2[H][M]->W2T[M][H] (bf16) -------------
__global__ __launch_bounds__(256)
void k_transpose_w(const float* __restrict__ W1, const float* __restrict__ W2,
                   unsigned short* __restrict__ W1T, unsigned short* __restrict__ W2T) {
  int idx = blockIdx.x * 256 + threadIdx.x;
  if (idx < MM * HH) {
    int hc = idx >> 8;          // 256 m per W1T row
    int m  = idx & 255;
    W1T[idx] = f2bf(W1[m * HH + hc]);
  } else {
    int j = idx - MM * HH;
    int m  = j >> 7;            // 128 h per W2T row
    int hd = j & 127;
    W2T[j] = f2bf(W2[hd * MM + m]);
  }
}

// ---------------- fused main ----------------
// grid = B * (N/128) = 256 blocks, 512 threads (8 waves: 2x4 of 64x64)
__global__ __launch_bounds__(512, 1)
void k_fused(const float* __restrict__ Ag, const float* __restrict__ hg,
             const unsigned short* __restrict__ hTg,
             const unsigned short* __restrict__ W1Tg,
             const unsigned short* __restrict__ W2Tg,
             const float* __restrict__ b1g, const float* __restrict__ b2g,
             float* __restrict__ outg) {
  __shared__ __align__(16) char smem[131072];
  __shared__ float smax[128];

  const int tid  = threadIdx.x;
  const int lane = tid & 63;
  const int wid  = tid >> 6;
  const int wr   = wid >> 2;     // 0..1
  const int wc   = wid & 3;      // 0..3
  const int l15  = lane & 15;
  const int lg   = lane >> 4;    // 0..3

  const int bid = blockIdx.x;
  const int b   = bid >> 3;
  const int r0  = (bid & 7) << 7;

  const float* Ab = Ag + ((size_t)b * NN + r0) * NN;
  const unsigned short* hTb = hTg + (size_t)b * MM * NN;

  f32x4 acc[4][4];
#pragma unroll
  for (int m = 0; m < 4; ++m)
#pragma unroll
    for (int n = 0; n < 4; ++n) acc[m][n] = f32x4{0.f, 0.f, 0.f, 0.f};

  float pmax = -1e30f;
  const int arow = tid >> 2;          // 0..127
  const int acg  = (tid & 3) << 4;    // 0,16,32,48

  // ============ phase 1: k = A @ h  (K = 1024, BK = 64) ============
  for (int k0 = 0; k0 < NN; k0 += 64) {
    // stage A: fp32 -> bf16, swizzled LDS [128][64], plus row-max
    {
      const float* src = Ab + (size_t)arow * NN + k0 + acg;
      float4 v0 = reinterpret_cast<const float4*>(src)[0];
      float4 v1 = reinterpret_cast<const float4*>(src)[1];
      float4 v2 = reinterpret_cast<const float4*>(src)[2];
      float4 v3 = reinterpret_cast<const float4*>(src)[3];
      float m0 = fmaxf(fmaxf(v0.x, v0.y), fmaxf(v0.z, v0.w));
      float m1 = fmaxf(fmaxf(v1.x, v1.y), fmaxf(v1.z, v1.w));
      float m2 = fmaxf(fmaxf(v2.x, v2.y), fmaxf(v2.z, v2.w));
      float m3 = fmaxf(fmaxf(v3.x, v3.y), fmaxf(v3.z, v3.w));
      pmax = fmaxf(pmax, fmaxf(fmaxf(m0, m1), fmaxf(m2, m3)));
      unsigned int p0 = pack2(v0.x, v0.y), p1 = pack2(v0.z, v0.w);
      unsigned int p2 = pack2(v1.x, v1.y), p3 = pack2(v1.z, v1.w);
      unsigned int p4 = pack2(v2.x, v2.y), p5 = pack2(v2.z, v2.w);
      unsigned int p6 = pack2(v3.x, v3.y), p7 = pack2(v3.z, v3.w);
      int base = arow * 128;
      int sw   = (arow & 7) << 4;
      *reinterpret_cast<uint4*>(smem + base + ((acg * 2) ^ sw))      = make_uint4(p0, p1, p2, p3);
      *reinterpret_cast<uint4*>(smem + base + ((acg * 2 + 16) ^ sw)) = make_uint4(p4, p5, p6, p7);
    }
    // stage hT tile [256][64] bf16, swizzled, at smem+16384
    {
      const int hc = (tid & 7) << 3;
#pragma unroll
      for (int i = 0; i < 4; ++i) {
        int hrow = (i << 6) + (tid >> 3);
        uint4 v = *reinterpret_cast<const uint4*>(hTb + (size_t)hrow * NN + k0 + hc);
        *reinterpret_cast<uint4*>(smem + 16384 + hrow * 128 + ((hc * 2) ^ ((hrow & 7) << 4))) = v;
      }
    }
    __syncthreads();
#pragma unroll
    for (int kk = 0; kk < 2; ++kk) {
      const int kb = (kk * 32 + (lg << 3)) * 2;
      bf16x8 af[4], bfr[4];
#pragma unroll
      for (int m = 0; m < 4; ++m) {
        int row = (wr << 6) + (m << 4) + l15;
        af[m] = *reinterpret_cast<const bf16x8*>(smem + row * 128 + (kb ^ ((row & 7) << 4)));
      }
#pragma unroll
      for (int n = 0; n < 4; ++n) {
        int col = (wc << 6) + (n << 4) + l15;
        bfr[n] = *reinterpret_cast<const bf16x8*>(smem + 16384 + col * 128 + (kb ^ ((col & 7) << 4)));
      }
#pragma unroll
      for (int m = 0; m < 4; ++m)
#pragma unroll
        for (int n = 0; n < 4; ++n)
          acc[m][n] = __builtin_amdgcn_mfma_f32_16x16x32_bf16(af[m], bfr[n], acc[m][n], 0, 0, 0);
    }
    __syncthreads();
  }

  // row-max finalize (4 staging threads per row are adjacent lanes)
  {
    float v = pmax;
    v = fmaxf(v, __shfl_xor(v, 1));
    v = fmaxf(v, __shfl_xor(v, 2));
    if ((tid & 3) == 0) smax[arow] = v;
  }

  // write k tile (/3, bf16) -> Kld [128][256] swizzled (rowB=512) at smem+0
  {
    const float inv3 = 1.0f / 3.0f;
#pragma unroll
    for (int m = 0; m < 4; ++m)
#pragma unroll
      for (int n = 0; n < 4; ++n) {
        int col = (wc << 6) + (n << 4) + l15;
#pragma unroll
        for (int j = 0; j < 4; ++j) {
          int row = (wr << 6) + (m << 4) + (lg << 2) + j;
          *reinterpret_cast<unsigned short*>(smem + row * 512 + ((col * 2) ^ ((row & 7) << 4))) =
              f2bf(acc[m][n][j] * inv3);
        }
      }
  }
  // stage W1T [128][256] bf16 -> smem+65536 (rowB=512), chunked copy
  {
#pragma unroll
    for (int i = 0; i < 8; ++i) {
      int c = (i << 9) + tid;        // 4096 chunks of 16B
      int row = c >> 5;
      int bc  = (c & 31) << 4;
      uint4 v = *reinterpret_cast<const uint4*>(W1Tg + ((size_t)c << 3));
      *reinterpret_cast<uint4*>(smem + 65536 + row * 512 + (bc ^ ((row & 7) << 4))) = v;
    }
  }
  __syncthreads();

  // ============ GEMM1: y[128][128] = k @ W1, waves 2x4 of 64x32 ============
  f32x4 acc1[4][2];
#pragma unroll
  for (int m = 0; m < 4; ++m)
#pragma unroll
    for (int n = 0; n < 2; ++n) acc1[m][n] = f32x4{0.f, 0.f, 0.f, 0.f};
#pragma unroll
  for (int kk = 0; kk < 8; ++kk) {
    const int kb = (kk * 32 + (lg << 3)) * 2;
    bf16x8 af[4], bfr[2];
#pragma unroll
    for (int m = 0; m < 4; ++m) {
      int row = (wr << 6) + (m << 4) + l15;
      af[m] = *reinterpret_cast<const bf16x8*>(smem + row * 512 + (kb ^ ((row & 7) << 4)));
    }
#pragma unroll
    for (int n = 0; n < 2; ++n) {
      int col = (wc << 5) + (n << 4) + l15;
      bfr[n] = *reinterpret_cast<const bf16x8*>(smem + 65536 + col * 512 + (kb ^ ((col & 7) << 4)));
    }
#pragma unroll
    for (int m = 0; m < 4; ++m)
#pragma unroll
      for (int n = 0; n < 2; ++n)
        acc1[m][n] = __builtin_amdgcn_mfma_f32_16x16x32_bf16(af[m], bfr[n], acc1[m][n], 0, 0, 0);
  }
  __syncthreads();  // done reading Kld / W1ld

  // c = relu(y + b1) -> Cld [128][128] bf16 (rowB=256) at smem+0
  {
#pragma unroll
    for (int n = 0; n < 2; ++n) {
      int col = (wc << 5) + (n << 4) + l15;
      float bias = b1g[col];
#pragma unroll
      for (int m = 0; m < 4; ++m)
#pragma unroll
        for (int j = 0; j < 4; ++j) {
          int row = (wr << 6) + (m << 4) + (lg << 2) + j;
          float v = fmaxf(acc1[m][n][j] + bias, 0.f);
          *reinterpret_cast<unsigned short*>(smem + row * 256 + ((col * 2) ^ ((row & 7) << 4))) = f2bf(v);
        }
    }
  }
  // stage W2T [256][128] bf16 -> smem+65536 (rowB=256)
  {
#pragma unroll
    for (int i = 0; i < 8; ++i) {
      int c = (i << 9) + tid;
      int row = c >> 4;
      int bc  = (c & 15) << 4;
      uint4 v = *reinterpret_cast<const uint4*>(W2Tg + ((size_t)c << 3));
      *reinterpret_cast<uint4*>(smem + 65536 + row * 256 + (bc ^ ((row & 7) << 4))) = v;
    }
  }
  __syncthreads();

  // ============ GEMM2: out2[128][256] = c @ W2, waves 2x4 of 64x64 ============
  f32x4 acc2[4][4];
#pragma unroll
  for (int m = 0; m < 4; ++m)
#pragma unroll
    for (int n = 0; n < 4; ++n) acc2[m][n] = f32x4{0.f, 0.f, 0.f, 0.f};
#pragma unroll
  for (int kk = 0; kk < 4; ++kk) {
    const int kb = (kk * 32 + (lg << 3)) * 2;
    bf16x8 af[4], bfr[4];
#pragma unroll
    for (int m = 0; m < 4; ++m) {
      int row = (wr << 6) + (m << 4) + l15;
      af[m] = *reinterpret_cast<const bf16x8*>(smem + row * 256 + (kb ^ ((row & 7) << 4)));
    }
#pragma unroll
    for (int n = 0; n < 4; ++n) {
      int col = (wc << 6) + (n << 4) + l15;
      bfr[n] = *reinterpret_cast<const bf16x8*>(smem + 65536 + col * 256 + (kb ^ ((col & 7) << 4)));
    }
#pragma unroll
    for (int m = 0; m < 4; ++m)
#pragma unroll
      for (int n = 0; n < 4; ++n)
        acc2[m][n] = __builtin_amdgcn_mfma_f32_16x16x32_bf16(af[m], bfr[n], acc2[m][n], 0, 0, 0);
  }

  // ============ epilogue: out = (out2+b2)*mask + h*(1-mask) ============
  {
#pragma unroll
    for (int n = 0; n < 4; ++n) {
      int col = (wc << 6) + (n << 4) + l15;
      float b2v = b2g[col];
#pragma unroll
      for (int m = 0; m < 4; ++m)
#pragma unroll
        for (int j = 0; j < 4; ++j) {
          int row = (wr << 6) + (m << 4) + (lg << 2) + j;
          float kv = acc2[m][n][j] + b2v;
          float mask = smax[row];
          size_t gidx = ((size_t)b * NN + r0 + row) * MM + col;
          float hv = hg[gidx];
          outg[gidx] = kv * mask + hv * (1.f - mask);
        }
    }
  }
}

extern "C" void kernel_launch(void* const* d_in, const int* in_sizes, int n_in,
                              void* d_out, int out_size, void* d_ws, size_t ws_size,
                              hipStream_t stream) {
  (void)in_sizes; (void)n_in; (void)out_size; (void)ws_size;
  const float* A  = (const float*)d_in[0];
  const float* h  = (const float*)d_in[1];
  const float* W1 = (const float*)d_in[2];
  const float* b1 = (const float*)d_in[3];
  const float* W2 = (const float*)d_in[4];
  const float* b2 = (const float*)d_in[5];
  float* out = (float*)d_out;

  unsigned short* hT  = (unsigned short*)d_ws;                              // 16 MiB
  unsigned short* W1T = (unsigned short*)((char*)d_ws + (size_t)BB * MM * NN * 2);
  unsigned short* W2T = W1T + MM * HH;

  k_transpose_h<<<BB * 64, 256, 0, stream>>>(h, hT);
  k_transpose_w<<<256, 256, 0, stream>>>(W1, W2, W1T, W2T);
  k_fused<<<BB * 8, 512, 0, stream>>>(A, h, hT, W1T, W2T, b1, b2, out);
}